// Round 10
// baseline (658.940 us; speedup 1.0000x reference)
//
#include <hip/hip_runtime.h>
#include <hip/hip_bf16.h>
#include <cstddef>
#include <cstdint>

#define FLT_MAX_C 3.402823466e+38f

typedef __attribute__((ext_vector_type(8))) __bf16 bf16x8;
typedef __attribute__((ext_vector_type(16))) float f32x16;

// Truncation-based fp32 -> bf16(hi) + bf16(lo) split, 8 elems -> two uint4.
// IDENTICAL to round 4/9 (bit-exact).
__device__ __forceinline__ void split8(const float* v, uint4& hi, uint4& lo) {
    uint32_t hu[8], lu[8];
#pragma unroll
    for (int e = 0; e < 8; ++e) {
        union { float f; uint32_t u; } a, t, d;
        a.f = v[e];
        t.u = a.u & 0xffff0000u;
        d.f = a.f - t.f;
        hu[e] = t.u;
        lu[e] = d.u;
    }
    hi.x = __builtin_amdgcn_perm(hu[1], hu[0], 0x07060302u);
    hi.y = __builtin_amdgcn_perm(hu[3], hu[2], 0x07060302u);
    hi.z = __builtin_amdgcn_perm(hu[5], hu[4], 0x07060302u);
    hi.w = __builtin_amdgcn_perm(hu[7], hu[6], 0x07060302u);
    lo.x = __builtin_amdgcn_perm(lu[1], lu[0], 0x07060302u);
    lo.y = __builtin_amdgcn_perm(lu[3], lu[2], 0x07060302u);
    lo.z = __builtin_amdgcn_perm(lu[5], lu[4], 0x07060302u);
    lo.w = __builtin_amdgcn_perm(lu[7], lu[6], 0x07060302u);
}

// ---------------------------------------------------------------------------
// Split-bf16 3-pass MFMA GEMM — per-output arithmetic BIT-IDENTICAL to
// rounds 4/9 (passed): same BK=32 K-loop, same two-chain accA(k0-15 mod 32)/
// accB(k16-31) structure, same 6-MFMA order, accA+accB at end. Only the
// SPATIAL decomposition changed (doesn't touch per-element accumulation):
//   block tile 32x64 (was 64x64), 2 waves (was 4), wave tile 32x32 unchanged.
//   -> s_b grid 752 -> 1504 blocks = 5.9 blocks/CU, LDS 24 KiB -> 6
//      resident blocks/CU = 6 independent barrier groups (was 3).
// Fragment-major LDS [k-slot][row][8 bf16]: conflict-free (r4-verified).
// ONE barrier/step; write_tile BEFORE load_regs (r8 bug); setprio on MFMA.
// 1D grid, by-inner + bijective XCD chunking. Requires Ma % 32 == 0.
// ---------------------------------------------------------------------------
template<bool ADD_BIAS>
__global__ __launch_bounds__(128) void gemm_mfma_split(
    const float* __restrict__ A, const float* __restrict__ Bm,
    const float* __restrict__ bias, float* __restrict__ C,
    int Ma, int Na, int K)
{
    // A: [buf][(slot*32 + row)*8], rows 0..31 ; B: [buf][(slot*64 + row)*8]
    __shared__ alignas(16) unsigned short As_hi[2][1024];
    __shared__ alignas(16) unsigned short As_lo[2][1024];
    __shared__ alignas(16) unsigned short Bs_hi[2][2048];
    __shared__ alignas(16) unsigned short Bs_lo[2][2048];

    const int nby = Ma >> 5;                 // 32-row M blocks
    // bijective XCD remap (m204)
    const int nwg = gridDim.x;
    const int orig = blockIdx.x;
    const int qq = nwg >> 3, rr = nwg & 7;
    const int xcd = orig & 7, lin = orig >> 3;
    const int wg = ((xcd < rr) ? xcd * (qq + 1) : rr * (qq + 1) + (xcd - rr) * qq) + lin;
    const int by = wg % nby;
    const int bx = wg / nby;

    const int m0 = by * 32;
    const int n0 = bx * 64;

    const int tid  = threadIdx.x;            // 0..127
    const int lane = tid & 63;
    const int wid  = tid >> 6;                // 0..1 -> N half (wn)

    // A staging: thread -> (row ra=tid&31, slot sa=tid>>5 in 0..3), 8 floats
    const int ra = tid & 31, sa = tid >> 5;
    // B staging: thread -> (row rb=tid&63, slots sb2 and sb2+2), 16 floats
    const int rb = tid & 63, sb2 = tid >> 6;

    const float* aB = A + (size_t)(m0 + ra) * K + sa * 8;
    const int gnb = n0 + rb;
    const float* bB = (gnb < Na) ? (Bm + (size_t)gnb * K + sb2 * 8) : nullptr;

    const int wOffA  = (sa * 32 + ra) * 8;          // ushort units
    const int wOffB0 = (sb2 * 64 + rb) * 8;
    const int wOffB1 = ((sb2 + 2) * 64 + rb) * 8;

    // fragment read offsets (8-lane groups span all 32 banks -> conflict-free)
    const int lr = lane & 31, kh = lane >> 5;
    const int brow = wid * 32 + lr;
    const int aOff0 = ((kh)     * 32 + lr) * 8;
    const int aOff1 = ((2 + kh) * 32 + lr) * 8;
    const int bOff0 = ((kh)     * 64 + brow) * 8;
    const int bOff1 = ((2 + kh) * 64 + brow) * 8;

    float ar_[8];
    float br_[16];
#pragma unroll
    for (int e = 0; e < 16; ++e) br_[e] = 0.0f;

    auto load_regs = [&](int s) {
        const int k0 = s << 5;
        const int ka = k0 + sa * 8;
        if (ka + 8 <= K) {
            float4 v0 = *(const float4*)(aB + k0);
            float4 v1 = *(const float4*)(aB + k0 + 4);
            ar_[0]=v0.x; ar_[1]=v0.y; ar_[2]=v0.z; ar_[3]=v0.w;
            ar_[4]=v1.x; ar_[5]=v1.y; ar_[6]=v1.z; ar_[7]=v1.w;
        } else {
#pragma unroll
            for (int e = 0; e < 8; ++e)
                ar_[e] = (ka + e < K) ? aB[k0 + e] : 0.0f;
        }
        if (bB) {
            const int kb0 = k0 + sb2 * 8;        // segment 0: slot sb2
            if (kb0 + 8 <= K) {
                float4 w0 = *(const float4*)(bB + k0);
                float4 w1 = *(const float4*)(bB + k0 + 4);
                br_[0]=w0.x; br_[1]=w0.y; br_[2]=w0.z; br_[3]=w0.w;
                br_[4]=w1.x; br_[5]=w1.y; br_[6]=w1.z; br_[7]=w1.w;
            } else {
#pragma unroll
                for (int e = 0; e < 8; ++e)
                    br_[e] = (kb0 + e < K) ? bB[k0 + e] : 0.0f;
            }
            const int kb1 = kb0 + 16;            // segment 1: slot sb2+2
            if (kb1 + 8 <= K) {
                float4 w0 = *(const float4*)(bB + k0 + 16);
                float4 w1 = *(const float4*)(bB + k0 + 20);
                br_[8]=w0.x;  br_[9]=w0.y;  br_[10]=w0.z; br_[11]=w0.w;
                br_[12]=w1.x; br_[13]=w1.y; br_[14]=w1.z; br_[15]=w1.w;
            } else {
#pragma unroll
                for (int e = 0; e < 8; ++e)
                    br_[8 + e] = (kb1 + e < K) ? bB[k0 + 16 + e] : 0.0f;
            }
        }
    };

    auto write_tile = [&](int buf) {
        uint4 hi, lo;
        split8(ar_, hi, lo);
        *(uint4*)&As_hi[buf][wOffA] = hi;
        *(uint4*)&As_lo[buf][wOffA] = lo;
        split8(br_, hi, lo);
        *(uint4*)&Bs_hi[buf][wOffB0] = hi;
        *(uint4*)&Bs_lo[buf][wOffB0] = lo;
        split8(br_ + 8, hi, lo);
        *(uint4*)&Bs_hi[buf][wOffB1] = hi;
        *(uint4*)&Bs_lo[buf][wOffB1] = lo;
    };

    f32x16 accA, accB;
#pragma unroll
    for (int i = 0; i < 16; ++i) { accA[i] = 0.0f; accB[i] = 0.0f; }

    const int nsteps = (K + 31) >> 5;
    load_regs(0);
    write_tile(0);
    if (nsteps > 1) load_regs(1);
    __syncthreads();

    for (int s = 0; s < nsteps; ++s) {
        const int cur = s & 1;

        // 1) fragment reads first — touch buf[cur], disjoint from staging
        bf16x8 a0h = *(const bf16x8*)&As_hi[cur][aOff0];
        bf16x8 a0l = *(const bf16x8*)&As_lo[cur][aOff0];
        bf16x8 a1h = *(const bf16x8*)&As_hi[cur][aOff1];
        bf16x8 a1l = *(const bf16x8*)&As_lo[cur][aOff1];
        bf16x8 b0h = *(const bf16x8*)&Bs_hi[cur][bOff0];
        bf16x8 b0l = *(const bf16x8*)&Bs_lo[cur][bOff0];
        bf16x8 b1h = *(const bf16x8*)&Bs_hi[cur][bOff1];
        bf16x8 b1l = *(const bf16x8*)&Bs_lo[cur][bOff1];

        // 2) write_tile BEFORE load_regs (ar_/br_ hold tile s+1 — r8 lesson)
        if (s + 1 < nsteps) write_tile(cur ^ 1);
        if (s + 2 < nsteps) load_regs(s + 2);

        // 3) MFMA: exact round-4 sequence (bit-identical accumulation)
        __builtin_amdgcn_s_setprio(1);
        accA = __builtin_amdgcn_mfma_f32_32x32x16_bf16(a0h, b0h, accA, 0,0,0);
        accB = __builtin_amdgcn_mfma_f32_32x32x16_bf16(a1h, b1h, accB, 0,0,0);
        accA = __builtin_amdgcn_mfma_f32_32x32x16_bf16(a0h, b0l, accA, 0,0,0);
        accB = __builtin_amdgcn_mfma_f32_32x32x16_bf16(a1h, b1l, accB, 0,0,0);
        accA = __builtin_amdgcn_mfma_f32_32x32x16_bf16(a0l, b0h, accA, 0,0,0);
        accB = __builtin_amdgcn_mfma_f32_32x32x16_bf16(a1l, b1h, accB, 0,0,0);
        __builtin_amdgcn_s_setprio(0);
        __syncthreads();
    }

    f32x16 acc;
#pragma unroll
    for (int i = 0; i < 16; ++i) acc[i] = accA[i] + accB[i];

    // C/D layout: col=lane&31, row=(reg&3)+8*(reg>>2)+4*(lane>>5)
    const int col = lane & 31;
    const int rbase = 4 * kh;
#pragma unroll
    for (int r = 0; r < 16; ++r) {
        const int row = (r & 3) + 8 * (r >> 2) + rbase;
        const int gm = m0 + row;                 // Ma % 32 == 0 -> valid
        const int gn = n0 + wid * 32 + col;
        if (gn < Na) {
            float v = acc[r];
            if (ADD_BIAS) v += bias[gn];
            C[(size_t)gm * Na + gn] = v;
        }
    }
}

// ---------------------------------------------------------------------------
// Per-batch-row masking pipeline — IDENTICAL to round 4/9 (passed).
// sB aliases the xbn region: each block stages its sB row into LDS before
// the barrier-ordered overwrite of the same row -> safe; no restrict on it.
// ---------------------------------------------------------------------------
__global__ __launch_bounds__(256) void rowproc_kernel(
    const float* __restrict__ zA,     // [B,1000]
    const float* sB,                  // [B,6000] (aliases xbn region)
    const float* __restrict__ phi,    // [B,6000]
    const float* __restrict__ psi,    // [B,6000]
    const float* __restrict__ decay,  // [6000]
    float* xbn, float* __restrict__ phin, float* __restrict__ psin,
    float* __restrict__ lam2)         // [B,1000]
{
    const int b = blockIdx.x;
    const int tid = threadIdx.x;
    const int lane = tid & 63;
    const int wid = tid >> 6;

    __shared__ float sig[6000];
    __shared__ float lam[1000];
    __shared__ int   wi[1000];
    __shared__ int   cw[1000];
    __shared__ float redf[4];

    const size_t rowTC = (size_t)b * 6000;
    const size_t rowM  = (size_t)b * 1000;

    // --- sigma + row min
    float lmin = FLT_MAX_C;
    for (int t = tid; t < 6000; t += 256) {
        float v = sB[rowTC + t] + zA[rowM + t / 6];
        sig[t] = v;
        lmin = fminf(lmin, v);
    }
#pragma unroll
    for (int off = 32; off > 0; off >>= 1)
        lmin = fminf(lmin, __shfl_down(lmin, off));
    if (lane == 0) redf[wid] = lmin;
    __syncthreads();
    if (tid == 0)
        redf[0] = fminf(fminf(redf[0], redf[1]), fminf(redf[2], redf[3]));
    __syncthreads();
    const float minv = redf[0];

    // --- per-column lam / winner cell; init cw
    for (int m = tid; m < 1000; m += 256) {
        float best = -FLT_MAX_C;
        int bj = 0;
#pragma unroll
        for (int j = 0; j < 6; ++j) {
            const int t = m * 6 + j;
            const float p = (1.0f - phi[rowTC + t]) * (sig[t] - minv);
            if (p > best) { best = p; bj = j; }
        }
        lam[m] = best;
        wi[m] = bj;
        cw[m] = 0;
    }
    __syncthreads();

    // --- top-50 of lam[1000]: wave 0 only, register-resident (ties -> low idx)
    if (wid == 0) {
        float lv[16];
        int wmask = 0;
#pragma unroll
        for (int j = 0; j < 16; ++j) {
            const int m = lane + (j << 6);
            lv[j] = (m < 1000) ? lam[m] : -FLT_MAX_C;
        }
        for (int it = 0; it < 50; ++it) {
            float bv = -FLT_MAX_C;
            int bi = 0x7fffffff;
#pragma unroll
            for (int j = 0; j < 16; ++j) {
                const int m = lane + (j << 6);
                const float v = lv[j];
                if (v > bv || (v == bv && m < bi)) { bv = v; bi = m; }
            }
#pragma unroll
            for (int off = 32; off > 0; off >>= 1) {
                const float ov = __shfl_xor(bv, off);
                const int oi  = __shfl_xor(bi, off);
                if (ov > bv || (ov == bv && oi < bi)) { bv = ov; bi = oi; }
            }
            if ((bi & 63) == lane) {
                const int jj = bi >> 6;
#pragma unroll
                for (int j = 0; j < 16; ++j)       // static indexing
                    if (j == jj) { lv[j] = -FLT_MAX_C; wmask |= (1 << j); }
            }
        }
#pragma unroll
        for (int j = 0; j < 16; ++j)
            if ((wmask >> j) & 1) cw[lane + (j << 6)] = 1;
    }
    __syncthreads();

    // --- write pass (per column), compute lam2
    for (int m = tid; m < 1000; m += 256) {
        const int won = cw[m];
        const int bj = wi[m];
        float cmax = -FLT_MAX_C;
        const size_t base = rowTC + (size_t)m * 6;
#pragma unroll
        for (int j = 0; j < 6; ++j) {
            const int t = m * 6 + j;
            const float y = (won && j == bj) ? tanhf(sig[t]) : 0.0f;
            const float pv = fmaxf(psi[base + j] * decay[t], y);
            const float fv = fmaxf(phi[base + j] * 0.5f, y);
            psin[base + j] = pv;
            xbn[base + j]  = pv;
            phin[base + j] = fv;
            cmax = fmaxf(cmax, pv);
        }
        lam2[rowM + m] = cmax;
    }
}

// ---------------------------------------------------------------------------
extern "C" void kernel_launch(void* const* d_in, const int* in_sizes, int n_in,
                              void* d_out, int out_size, void* d_ws, size_t ws_size,
                              hipStream_t stream)
{
    const float* x_a   = (const float*)d_in[0];  // [512,2048]
    const float* x_b   = (const float*)d_in[1];  // [512,6000]
    const float* phi   = (const float*)d_in[2];  // [512,6000]
    const float* psi   = (const float*)d_in[3];  // [512,6000]
    const float* W_a   = (const float*)d_in[4];  // [1000,2048]
    const float* W_b   = (const float*)d_in[5];  // [6000,6000]
    const float* W_d   = (const float*)d_in[6];  // [2048,1000]
    const float* b_d   = (const float*)d_in[7];  // [2048]
    const float* decay = (const float*)d_in[8];  // [6000]

    float* out  = (float*)d_out;                       // [512,2048]
    float* xbn  = out + (size_t)512 * 2048;            // [512,6000]
    float* phin = xbn + (size_t)512 * 6000;            // [512,6000]
    float* psin = phin + (size_t)512 * 6000;           // [512,6000]

    float* lam2 = (float*)d_ws;          // [512,1000] (2 MB)

    // Staging (round-4/9 proven): z_a in out region (consumed by rowproc
    // before decode GEMM overwrites out); s_b in xbn region (rowproc stages
    // its row into LDS before overwriting).
    float* z_a = out;
    float* s_b = xbn;

    dim3 blk(128);
    // z_a = x_a @ W_a^T   [512,1000], K=2048; grid = 16 bx * 16 by = 256
    gemm_mfma_split<false><<<dim3(16 * 16), blk, 0, stream>>>(x_a, W_a, nullptr, z_a, 512, 1000, 2048);
    // s_b = x_b @ W_b^T   [512,6000], K=6000; grid = 94 bx * 16 by = 1504
    gemm_mfma_split<false><<<dim3(94 * 16), blk, 0, stream>>>(x_b, W_b, nullptr, s_b, 512, 6000, 6000);
    // masking pipeline
    rowproc_kernel<<<512, dim3(256), 0, stream>>>(z_a, s_b, phi, psi, decay, xbn, phin, psin, lam2);
    // out = lam2 @ W_d^T + b_d   [512,2048], K=1000; grid = 32 bx * 16 by = 512
    gemm_mfma_split<true><<<dim3(32 * 16), blk, 0, stream>>>(lam2, W_d, b_d, out, 512, 2048, 1000);
}

// Round 11
// 497.756 us; speedup vs baseline: 1.3238x; 1.3238x over previous
//
#include <hip/hip_runtime.h>
#include <hip/hip_bf16.h>
#include <cstddef>
#include <cstdint>

#define FLT_MAX_C 3.402823466e+38f

typedef __attribute__((ext_vector_type(8))) __bf16 bf16x8;
typedef __attribute__((ext_vector_type(16))) float f32x16;

// Truncation-based fp32 -> bf16(hi) + bf16(lo) split, 8 elems -> two uint4.
// IDENTICAL to round 4/9 (bit-exact).
__device__ __forceinline__ void split8(const float* v, uint4& hi, uint4& lo) {
    uint32_t hu[8], lu[8];
#pragma unroll
    for (int e = 0; e < 8; ++e) {
        union { float f; uint32_t u; } a, t, d;
        a.f = v[e];
        t.u = a.u & 0xffff0000u;
        d.f = a.f - t.f;
        hu[e] = t.u;
        lu[e] = d.u;
    }
    hi.x = __builtin_amdgcn_perm(hu[1], hu[0], 0x07060302u);
    hi.y = __builtin_amdgcn_perm(hu[3], hu[2], 0x07060302u);
    hi.z = __builtin_amdgcn_perm(hu[5], hu[4], 0x07060302u);
    hi.w = __builtin_amdgcn_perm(hu[7], hu[6], 0x07060302u);
    lo.x = __builtin_amdgcn_perm(lu[1], lu[0], 0x07060302u);
    lo.y = __builtin_amdgcn_perm(lu[3], lu[2], 0x07060302u);
    lo.z = __builtin_amdgcn_perm(lu[5], lu[4], 0x07060302u);
    lo.w = __builtin_amdgcn_perm(lu[7], lu[6], 0x07060302u);
}

// ---------------------------------------------------------------------------
// Split-bf16 3-pass MFMA GEMM — per-output arithmetic BIT-IDENTICAL to
// rounds 4/9 (passed): 64x64 block, BK=32 K-steps in ascending order, two
// chains accA (k mod 32 in 0-15) / accB (16-31), 6-MFMA order hh,hh,hl,hl,
// lh,lh, accA+accB at the end.
// NEW (scheduling only): 3-buffer LDS rotation + register fragment
// ping-pong. Step s runs MFMA on PRE-LOADED fragments while prefetching
// frags(s+1) from LDS, converting+writing tile s+2, and issuing global
// loads for tile s+3. ds_read latency is off the critical path.
// Hazards: read buf[(s+1)%3] written at s-1 (barrier-ordered); write
// buf[(s+2)%3] last read at s-2; write_tile(s+2) consumes ar_/br_ BEFORE
// load_regs(s+3) refills them (round-8 lesson).
// Fragment-major LDS [k-slot][row][8 bf16]: conflict-free (r4-verified).
// LDS = 48 KiB -> 3 blocks/CU. Requires Ma % 64 == 0 and even nsteps
// (K=6000->188, 2048->64, 1000->32: all even).
// ---------------------------------------------------------------------------
template<bool ADD_BIAS>
__global__ __launch_bounds__(256) void gemm_mfma_split(
    const float* __restrict__ A, const float* __restrict__ Bm,
    const float* __restrict__ bias, float* __restrict__ C,
    int Ma, int Na, int K)
{
    __shared__ alignas(16) unsigned short As_hi[3][2048];
    __shared__ alignas(16) unsigned short As_lo[3][2048];
    __shared__ alignas(16) unsigned short Bs_hi[3][2048];
    __shared__ alignas(16) unsigned short Bs_lo[3][2048];

    const int nby = Ma >> 6;
    // bijective XCD remap (m204)
    const int nwg = gridDim.x;
    const int orig = blockIdx.x;
    const int qq = nwg >> 3, rr = nwg & 7;
    const int xcd = orig & 7, lin = orig >> 3;
    const int wg = ((xcd < rr) ? xcd * (qq + 1) : rr * (qq + 1) + (xcd - rr) * qq) + lin;
    const int by = wg % nby;
    const int bx = wg / nby;

    const int m0 = by * 64;
    const int n0 = bx * 64;

    const int tid  = threadIdx.x;
    const int lane = tid & 63;
    const int wid  = tid >> 6;
    const int wm   = wid >> 1;
    const int wn   = wid & 1;

    // staging: thread -> (row ra, k-slot sa); stages 8 floats of A and of B
    const int ra = tid & 63, sa = tid >> 6;

    const float* aB = A + (size_t)(m0 + ra) * K + sa * 8;
    const int gnb = n0 + ra;
    const float* bB = (gnb < Na) ? (Bm + (size_t)gnb * K + sa * 8) : nullptr;

    const int wOff = (sa * 64 + ra) * 8;   // ushort units; wave-contiguous 1 KiB

    // fragment read offsets (half-wave = 512 contiguous bytes, conflict-free)
    const int lr = lane & 31, kh = lane >> 5;
    const int arow = wm * 32 + lr;
    const int brow = wn * 32 + lr;
    const int aOff0 = ((kh)     * 64 + arow) * 8;
    const int aOff1 = ((2 + kh) * 64 + arow) * 8;
    const int bOff0 = ((kh)     * 64 + brow) * 8;
    const int bOff1 = ((2 + kh) * 64 + brow) * 8;

    float ar_[8];
    float br_[8];
#pragma unroll
    for (int e = 0; e < 8; ++e) br_[e] = 0.0f;

    auto load_regs = [&](int s) {
        const int k0 = s << 5;
        const int ka = k0 + sa * 8;
        if (ka + 8 <= K) {
            float4 v0 = *(const float4*)(aB + k0);
            float4 v1 = *(const float4*)(aB + k0 + 4);
            ar_[0]=v0.x; ar_[1]=v0.y; ar_[2]=v0.z; ar_[3]=v0.w;
            ar_[4]=v1.x; ar_[5]=v1.y; ar_[6]=v1.z; ar_[7]=v1.w;
            if (bB) {
                float4 w0 = *(const float4*)(bB + k0);
                float4 w1 = *(const float4*)(bB + k0 + 4);
                br_[0]=w0.x; br_[1]=w0.y; br_[2]=w0.z; br_[3]=w0.w;
                br_[4]=w1.x; br_[5]=w1.y; br_[6]=w1.z; br_[7]=w1.w;
            }
        } else {
#pragma unroll
            for (int e = 0; e < 8; ++e)
                ar_[e] = (ka + e < K) ? aB[k0 + e] : 0.0f;
            if (bB) {
#pragma unroll
                for (int e = 0; e < 8; ++e)
                    br_[e] = (ka + e < K) ? bB[k0 + e] : 0.0f;
            }
        }
    };

    auto write_tile = [&](int buf) {
        uint4 hi, lo;
        split8(ar_, hi, lo);
        *(uint4*)&As_hi[buf][wOff] = hi;
        *(uint4*)&As_lo[buf][wOff] = lo;
        split8(br_, hi, lo);
        *(uint4*)&Bs_hi[buf][wOff] = hi;
        *(uint4*)&Bs_lo[buf][wOff] = lo;
    };

    struct Frags { bf16x8 a0h, a0l, a1h, a1l, b0h, b0l, b1h, b1l; };
    auto read_frags = [&](int bi, Frags& f) {
        f.a0h = *(const bf16x8*)&As_hi[bi][aOff0];
        f.a0l = *(const bf16x8*)&As_lo[bi][aOff0];
        f.a1h = *(const bf16x8*)&As_hi[bi][aOff1];
        f.a1l = *(const bf16x8*)&As_lo[bi][aOff1];
        f.b0h = *(const bf16x8*)&Bs_hi[bi][bOff0];
        f.b0l = *(const bf16x8*)&Bs_lo[bi][bOff0];
        f.b1h = *(const bf16x8*)&Bs_hi[bi][bOff1];
        f.b1l = *(const bf16x8*)&Bs_lo[bi][bOff1];
    };

    f32x16 accA, accB;
#pragma unroll
    for (int i = 0; i < 16; ++i) { accA[i] = 0.0f; accB[i] = 0.0f; }

    auto mfma6 = [&](const Frags& f) {
        __builtin_amdgcn_s_setprio(1);
        accA = __builtin_amdgcn_mfma_f32_32x32x16_bf16(f.a0h, f.b0h, accA, 0,0,0);
        accB = __builtin_amdgcn_mfma_f32_32x32x16_bf16(f.a1h, f.b1h, accB, 0,0,0);
        accA = __builtin_amdgcn_mfma_f32_32x32x16_bf16(f.a0h, f.b0l, accA, 0,0,0);
        accB = __builtin_amdgcn_mfma_f32_32x32x16_bf16(f.a1h, f.b1l, accB, 0,0,0);
        accA = __builtin_amdgcn_mfma_f32_32x32x16_bf16(f.a0l, f.b0h, accA, 0,0,0);
        accB = __builtin_amdgcn_mfma_f32_32x32x16_bf16(f.a1l, f.b1h, accB, 0,0,0);
        __builtin_amdgcn_s_setprio(0);
    };

    const int nsteps = (K + 31) >> 5;      // even for all K used here

    // prologue: tiles 0,1 staged to buf 0,1; tile 2 in regs; frags(0) in fX
    load_regs(0);
    write_tile(0);
    if (nsteps > 1) { load_regs(1); write_tile(1); }
    if (nsteps > 2) load_regs(2);
    __syncthreads();

    Frags fX, fY;
    read_frags(0, fX);

    for (int s = 0; s < nsteps; s += 2) {
        // ---- body s (compute fX, prefetch into fY)
        if (s + 1 < nsteps) read_frags((s + 1) % 3, fY);
        if (s + 2 < nsteps) write_tile((s + 2) % 3);   // consumes regs (tile s+2)
        if (s + 3 < nsteps) load_regs(s + 3);          // refill regs (tile s+3)
        mfma6(fX);
        __syncthreads();

        // ---- body s+1 (compute fY, prefetch into fX)
        if (s + 2 < nsteps) read_frags((s + 2) % 3, fX);
        if (s + 3 < nsteps) write_tile((s + 3) % 3);   // consumes regs (tile s+3)
        if (s + 4 < nsteps) load_regs(s + 4);          // refill regs (tile s+4)
        if (s + 1 < nsteps) mfma6(fY);
        __syncthreads();
    }

    f32x16 acc;
#pragma unroll
    for (int i = 0; i < 16; ++i) acc[i] = accA[i] + accB[i];

    // C/D layout: col=lane&31, row=(reg&3)+8*(reg>>2)+4*(lane>>5)
    const int col = lane & 31;
    const int rbase = 4 * kh;
#pragma unroll
    for (int r = 0; r < 16; ++r) {
        const int row = (r & 3) + 8 * (r >> 2) + rbase;
        const int gm = m0 + wm * 32 + row;       // Ma % 64 == 0 -> valid
        const int gn = n0 + wn * 32 + col;
        if (gn < Na) {
            float v = acc[r];
            if (ADD_BIAS) v += bias[gn];
            C[(size_t)gm * Na + gn] = v;
        }
    }
}

// ---------------------------------------------------------------------------
// Per-batch-row masking pipeline — IDENTICAL to round 4/9 (passed).
// sB aliases the xbn region: each block stages its sB row into LDS before
// the barrier-ordered overwrite of the same row -> safe; no restrict on it.
// ---------------------------------------------------------------------------
__global__ __launch_bounds__(256) void rowproc_kernel(
    const float* __restrict__ zA,     // [B,1000]
    const float* sB,                  // [B,6000] (aliases xbn region)
    const float* __restrict__ phi,    // [B,6000]
    const float* __restrict__ psi,    // [B,6000]
    const float* __restrict__ decay,  // [6000]
    float* xbn, float* __restrict__ phin, float* __restrict__ psin,
    float* __restrict__ lam2)         // [B,1000]
{
    const int b = blockIdx.x;
    const int tid = threadIdx.x;
    const int lane = tid & 63;
    const int wid = tid >> 6;

    __shared__ float sig[6000];
    __shared__ float lam[1000];
    __shared__ int   wi[1000];
    __shared__ int   cw[1000];
    __shared__ float redf[4];

    const size_t rowTC = (size_t)b * 6000;
    const size_t rowM  = (size_t)b * 1000;

    // --- sigma + row min
    float lmin = FLT_MAX_C;
    for (int t = tid; t < 6000; t += 256) {
        float v = sB[rowTC + t] + zA[rowM + t / 6];
        sig[t] = v;
        lmin = fminf(lmin, v);
    }
#pragma unroll
    for (int off = 32; off > 0; off >>= 1)
        lmin = fminf(lmin, __shfl_down(lmin, off));
    if (lane == 0) redf[wid] = lmin;
    __syncthreads();
    if (tid == 0)
        redf[0] = fminf(fminf(redf[0], redf[1]), fminf(redf[2], redf[3]));
    __syncthreads();
    const float minv = redf[0];

    // --- per-column lam / winner cell; init cw
    for (int m = tid; m < 1000; m += 256) {
        float best = -FLT_MAX_C;
        int bj = 0;
#pragma unroll
        for (int j = 0; j < 6; ++j) {
            const int t = m * 6 + j;
            const float p = (1.0f - phi[rowTC + t]) * (sig[t] - minv);
            if (p > best) { best = p; bj = j; }
        }
        lam[m] = best;
        wi[m] = bj;
        cw[m] = 0;
    }
    __syncthreads();

    // --- top-50 of lam[1000]: wave 0 only, register-resident (ties -> low idx)
    if (wid == 0) {
        float lv[16];
        int wmask = 0;
#pragma unroll
        for (int j = 0; j < 16; ++j) {
            const int m = lane + (j << 6);
            lv[j] = (m < 1000) ? lam[m] : -FLT_MAX_C;
        }
        for (int it = 0; it < 50; ++it) {
            float bv = -FLT_MAX_C;
            int bi = 0x7fffffff;
#pragma unroll
            for (int j = 0; j < 16; ++j) {
                const int m = lane + (j << 6);
                const float v = lv[j];
                if (v > bv || (v == bv && m < bi)) { bv = v; bi = m; }
            }
#pragma unroll
            for (int off = 32; off > 0; off >>= 1) {
                const float ov = __shfl_xor(bv, off);
                const int oi  = __shfl_xor(bi, off);
                if (ov > bv || (ov == bv && oi < bi)) { bv = ov; bi = oi; }
            }
            if ((bi & 63) == lane) {
                const int jj = bi >> 6;
#pragma unroll
                for (int j = 0; j < 16; ++j)       // static indexing
                    if (j == jj) { lv[j] = -FLT_MAX_C; wmask |= (1 << j); }
            }
        }
#pragma unroll
        for (int j = 0; j < 16; ++j)
            if ((wmask >> j) & 1) cw[lane + (j << 6)] = 1;
    }
    __syncthreads();

    // --- write pass (per column), compute lam2
    for (int m = tid; m < 1000; m += 256) {
        const int won = cw[m];
        const int bj = wi[m];
        float cmax = -FLT_MAX_C;
        const size_t base = rowTC + (size_t)m * 6;
#pragma unroll
        for (int j = 0; j < 6; ++j) {
            const int t = m * 6 + j;
            const float y = (won && j == bj) ? tanhf(sig[t]) : 0.0f;
            const float pv = fmaxf(psi[base + j] * decay[t], y);
            const float fv = fmaxf(phi[base + j] * 0.5f, y);
            psin[base + j] = pv;
            xbn[base + j]  = pv;
            phin[base + j] = fv;
            cmax = fmaxf(cmax, pv);
        }
        lam2[rowM + m] = cmax;
    }
}

// ---------------------------------------------------------------------------
extern "C" void kernel_launch(void* const* d_in, const int* in_sizes, int n_in,
                              void* d_out, int out_size, void* d_ws, size_t ws_size,
                              hipStream_t stream)
{
    const float* x_a   = (const float*)d_in[0];  // [512,2048]
    const float* x_b   = (const float*)d_in[1];  // [512,6000]
    const float* phi   = (const float*)d_in[2];  // [512,6000]
    const float* psi   = (const float*)d_in[3];  // [512,6000]
    const float* W_a   = (const float*)d_in[4];  // [1000,2048]
    const float* W_b   = (const float*)d_in[5];  // [6000,6000]
    const float* W_d   = (const float*)d_in[6];  // [2048,1000]
    const float* b_d   = (const float*)d_in[7];  // [2048]
    const float* decay = (const float*)d_in[8];  // [6000]

    float* out  = (float*)d_out;                       // [512,2048]
    float* xbn  = out + (size_t)512 * 2048;            // [512,6000]
    float* phin = xbn + (size_t)512 * 6000;            // [512,6000]
    float* psin = phin + (size_t)512 * 6000;           // [512,6000]

    float* lam2 = (float*)d_ws;          // [512,1000] (2 MB)

    // Staging (round-4/9 proven): z_a in out region (consumed by rowproc
    // before decode GEMM overwrites out); s_b in xbn region (rowproc stages
    // its row into LDS before overwriting).
    float* z_a = out;
    float* s_b = xbn;

    dim3 blk(256);
    // z_a = x_a @ W_a^T   [512,1000], K=2048; grid = 16 bx * 8 by
    gemm_mfma_split<false><<<dim3(16 * 8), blk, 0, stream>>>(x_a, W_a, nullptr, z_a, 512, 1000, 2048);
    // s_b = x_b @ W_b^T   [512,6000], K=6000; grid = 94 bx * 8 by = 752
    gemm_mfma_split<false><<<dim3(94 * 8), blk, 0, stream>>>(x_b, W_b, nullptr, s_b, 512, 6000, 6000);
    // masking pipeline
    rowproc_kernel<<<512, blk, 0, stream>>>(z_a, s_b, phi, psi, decay, xbn, phin, psin, lam2);
    // out = lam2 @ W_d^T + b_d   [512,2048], K=1000; grid = 32 bx * 8 by
    gemm_mfma_split<true><<<dim3(32 * 8), blk, 0, stream>>>(lam2, W_d, b_d, out, 512, 2048, 1000);
}

// Round 12
// 414.095 us; speedup vs baseline: 1.5913x; 1.2020x over previous
//
#include <hip/hip_runtime.h>
#include <hip/hip_bf16.h>
#include <cstddef>
#include <cstdint>

#define FLT_MAX_C 3.402823466e+38f

typedef __attribute__((ext_vector_type(8))) __bf16 bf16x8;
typedef __attribute__((ext_vector_type(16))) float f32x16;

// Truncation-based fp32 -> bf16(hi) + bf16(lo) split, 8 elems -> two uint4.
// IDENTICAL to round 4/9 (bit-exact).
__device__ __forceinline__ void split8(const float* v, uint4& hi, uint4& lo) {
    uint32_t hu[8], lu[8];
#pragma unroll
    for (int e = 0; e < 8; ++e) {
        union { float f; uint32_t u; } a, t, d;
        a.f = v[e];
        t.u = a.u & 0xffff0000u;
        d.f = a.f - t.f;
        hu[e] = t.u;
        lu[e] = d.u;
    }
    hi.x = __builtin_amdgcn_perm(hu[1], hu[0], 0x07060302u);
    hi.y = __builtin_amdgcn_perm(hu[3], hu[2], 0x07060302u);
    hi.z = __builtin_amdgcn_perm(hu[5], hu[4], 0x07060302u);
    hi.w = __builtin_amdgcn_perm(hu[7], hu[6], 0x07060302u);
    lo.x = __builtin_amdgcn_perm(lu[1], lu[0], 0x07060302u);
    lo.y = __builtin_amdgcn_perm(lu[3], lu[2], 0x07060302u);
    lo.z = __builtin_amdgcn_perm(lu[5], lu[4], 0x07060302u);
    lo.w = __builtin_amdgcn_perm(lu[7], lu[6], 0x07060302u);
}

// LDS-only barrier: drain ds ops (lgkmcnt) so writes are visible, then
// s_barrier — but leave GLOBAL loads (vmcnt) in flight across the barrier.
// __syncthreads() would emit s_waitcnt vmcnt(0) and serialize every K-step
// on HBM latency (m97 stall). Loads land in private VGPRs consumed by the
// same wave; the compiler inserts the vmcnt wait at the use site.
__device__ __forceinline__ void lds_barrier() {
    asm volatile("s_waitcnt lgkmcnt(0)" ::: "memory");
    __builtin_amdgcn_s_barrier();
}

// ---------------------------------------------------------------------------
// Split-bf16 3-pass MFMA GEMM — per-output arithmetic BIT-IDENTICAL to
// rounds 4/9 (passed): 64x64 block, BK=32 K-steps ascending, two chains
// accA (k mod 32 in 0-15) / accB (16-31), 6-MFMA order hh,hh,hl,hl,lh,lh,
// accA+accB at end. Geometry identical to r9 (32 KiB LDS, 256 thr, 4 waves).
// NEW (sync only): counted-wait barrier (lds_barrier) in the K-loop keeps
// global prefetch loads in flight across barriers; two staging register
// sets (R0/R1, static ping-pong, 2-step unroll) give each load 2 barrier
// crossings (~2 steps) to complete before its write_tile use.
// Requires Ma % 64 == 0. nsteps even for all K used (188 / 64 / 32).
// ---------------------------------------------------------------------------
template<bool ADD_BIAS>
__global__ __launch_bounds__(256) void gemm_mfma_split(
    const float* __restrict__ A, const float* __restrict__ Bm,
    const float* __restrict__ bias, float* __restrict__ C,
    int Ma, int Na, int K)
{
    __shared__ alignas(16) unsigned short As_hi[2][2048];
    __shared__ alignas(16) unsigned short As_lo[2][2048];
    __shared__ alignas(16) unsigned short Bs_hi[2][2048];
    __shared__ alignas(16) unsigned short Bs_lo[2][2048];

    const int nby = Ma >> 6;
    // bijective XCD remap (m204)
    const int nwg = gridDim.x;
    const int orig = blockIdx.x;
    const int qq = nwg >> 3, rr = nwg & 7;
    const int xcd = orig & 7, lin = orig >> 3;
    const int wg = ((xcd < rr) ? xcd * (qq + 1) : rr * (qq + 1) + (xcd - rr) * qq) + lin;
    const int by = wg % nby;
    const int bx = wg / nby;

    const int m0 = by * 64;
    const int n0 = bx * 64;

    const int tid  = threadIdx.x;
    const int lane = tid & 63;
    const int wid  = tid >> 6;
    const int wm   = wid >> 1;
    const int wn   = wid & 1;

    // staging: thread -> (row ra, k-slot sa); stages 8 floats of A and of B
    const int ra = tid & 63, sa = tid >> 6;

    const float* aB = A + (size_t)(m0 + ra) * K + sa * 8;
    const int gnb = n0 + ra;
    const float* bB = (gnb < Na) ? (Bm + (size_t)gnb * K + sa * 8) : nullptr;

    const int wOff = (sa * 64 + ra) * 8;   // ushort units; wave-contiguous 1 KiB

    // fragment read offsets (half-wave = 512 contiguous bytes, conflict-free)
    const int lr = lane & 31, kh = lane >> 5;
    const int arow = wm * 32 + lr;
    const int brow = wn * 32 + lr;
    const int aOff0 = ((kh)     * 64 + arow) * 8;
    const int aOff1 = ((2 + kh) * 64 + arow) * 8;
    const int bOff0 = ((kh)     * 64 + brow) * 8;
    const int bOff1 = ((2 + kh) * 64 + brow) * 8;

    // two staging register sets (static ping-pong; rule-20 safe)
    float ar0[8], br0[8], ar1[8], br1[8];
#pragma unroll
    for (int e = 0; e < 8; ++e) { br0[e] = 0.0f; br1[e] = 0.0f; }

    auto load_regs = [&](float* arr, float* brr, int s) {
        const int k0 = s << 5;
        const int ka = k0 + sa * 8;
        if (ka + 8 <= K) {
            float4 v0 = *(const float4*)(aB + k0);
            float4 v1 = *(const float4*)(aB + k0 + 4);
            arr[0]=v0.x; arr[1]=v0.y; arr[2]=v0.z; arr[3]=v0.w;
            arr[4]=v1.x; arr[5]=v1.y; arr[6]=v1.z; arr[7]=v1.w;
            if (bB) {
                float4 w0 = *(const float4*)(bB + k0);
                float4 w1 = *(const float4*)(bB + k0 + 4);
                brr[0]=w0.x; brr[1]=w0.y; brr[2]=w0.z; brr[3]=w0.w;
                brr[4]=w1.x; brr[5]=w1.y; brr[6]=w1.z; brr[7]=w1.w;
            }
        } else {
#pragma unroll
            for (int e = 0; e < 8; ++e)
                arr[e] = (ka + e < K) ? aB[k0 + e] : 0.0f;
            if (bB) {
#pragma unroll
                for (int e = 0; e < 8; ++e)
                    brr[e] = (ka + e < K) ? bB[k0 + e] : 0.0f;
            }
        }
    };

    auto write_tile = [&](int buf, const float* arr, const float* brr) {
        uint4 hi, lo;
        split8(arr, hi, lo);
        *(uint4*)&As_hi[buf][wOff] = hi;
        *(uint4*)&As_lo[buf][wOff] = lo;
        split8(brr, hi, lo);
        *(uint4*)&Bs_hi[buf][wOff] = hi;
        *(uint4*)&Bs_lo[buf][wOff] = lo;
    };

    f32x16 accA, accB;
#pragma unroll
    for (int i = 0; i < 16; ++i) { accA[i] = 0.0f; accB[i] = 0.0f; }

    auto step_body = [&](int bufR, int bufW, const float* arr, const float* brr,
                         float* arrN, float* brrN, int s) {
        // 1) fragment reads — buf[bufR], disjoint from staging writes
        bf16x8 a0h = *(const bf16x8*)&As_hi[bufR][aOff0];
        bf16x8 a0l = *(const bf16x8*)&As_lo[bufR][aOff0];
        bf16x8 a1h = *(const bf16x8*)&As_hi[bufR][aOff1];
        bf16x8 a1l = *(const bf16x8*)&As_lo[bufR][aOff1];
        bf16x8 b0h = *(const bf16x8*)&Bs_hi[bufR][bOff0];
        bf16x8 b0l = *(const bf16x8*)&Bs_lo[bufR][bOff0];
        bf16x8 b1h = *(const bf16x8*)&Bs_hi[bufR][bOff1];
        bf16x8 b1l = *(const bf16x8*)&Bs_lo[bufR][bOff1];

        // 2) stage tile s+1 (regs loaded 2 steps ago; vmcnt wait auto at use),
        //    then issue loads for tile s+3 into the other set (r8 order lesson)
        const int nst = (K + 31) >> 5;
        if (s + 1 < nst) write_tile(bufW, arr, brr);
        if (s + 3 < nst) load_regs(arrN, brrN, s + 3);

        // 3) MFMA: exact round-4 sequence (bit-identical accumulation)
        __builtin_amdgcn_s_setprio(1);
        accA = __builtin_amdgcn_mfma_f32_32x32x16_bf16(a0h, b0h, accA, 0,0,0);
        accB = __builtin_amdgcn_mfma_f32_32x32x16_bf16(a1h, b1h, accB, 0,0,0);
        accA = __builtin_amdgcn_mfma_f32_32x32x16_bf16(a0h, b0l, accA, 0,0,0);
        accB = __builtin_amdgcn_mfma_f32_32x32x16_bf16(a1h, b1l, accB, 0,0,0);
        accA = __builtin_amdgcn_mfma_f32_32x32x16_bf16(a0l, b0h, accA, 0,0,0);
        accB = __builtin_amdgcn_mfma_f32_32x32x16_bf16(a1l, b1h, accB, 0,0,0);
        __builtin_amdgcn_s_setprio(0);

        // 4) LDS-only barrier: ds ops drained, global loads stay in flight
        lds_barrier();
    };

    const int nsteps = (K + 31) >> 5;      // even for all K used here

    // prologue: tile 0 staged to buf0; R0 <- tile 1; R1 <- tile 2 (in flight)
    load_regs(ar0, br0, 0);
    write_tile(0, ar0, br0);
    if (nsteps > 1) load_regs(ar0, br0, 1);
    if (nsteps > 2) load_regs(ar1, br1, 2);
    __syncthreads();

    for (int s = 0; s < nsteps; s += 2) {
        // even step: read buf0, write buf1 <- R0 (tile s+1), issue R0 <- s+3
        step_body(0, 1, ar0, br0, ar0, br0, s);
        // odd step: read buf1, write buf0 <- R1 (tile s+2), issue R1 <- s+4
        if (s + 1 < nsteps)
            step_body(1, 0, ar1, br1, ar1, br1, s + 1);
    }

    f32x16 acc;
#pragma unroll
    for (int i = 0; i < 16; ++i) acc[i] = accA[i] + accB[i];

    // C/D layout: col=lane&31, row=(reg&3)+8*(reg>>2)+4*(lane>>5)
    const int col = lane & 31;
    const int rbase = 4 * kh;
#pragma unroll
    for (int r = 0; r < 16; ++r) {
        const int row = (r & 3) + 8 * (r >> 2) + rbase;
        const int gm = m0 + wm * 32 + row;       // Ma % 64 == 0 -> valid
        const int gn = n0 + wn * 32 + col;
        if (gn < Na) {
            float v = acc[r];
            if (ADD_BIAS) v += bias[gn];
            C[(size_t)gm * Na + gn] = v;
        }
    }
}

// ---------------------------------------------------------------------------
// Per-batch-row masking pipeline — IDENTICAL to round 4/9 (passed).
// sB aliases the xbn region: each block stages its sB row into LDS before
// the barrier-ordered overwrite of the same row -> safe; no restrict on it.
// ---------------------------------------------------------------------------
__global__ __launch_bounds__(256) void rowproc_kernel(
    const float* __restrict__ zA,     // [B,1000]
    const float* sB,                  // [B,6000] (aliases xbn region)
    const float* __restrict__ phi,    // [B,6000]
    const float* __restrict__ psi,    // [B,6000]
    const float* __restrict__ decay,  // [6000]
    float* xbn, float* __restrict__ phin, float* __restrict__ psin,
    float* __restrict__ lam2)         // [B,1000]
{
    const int b = blockIdx.x;
    const int tid = threadIdx.x;
    const int lane = tid & 63;
    const int wid = tid >> 6;

    __shared__ float sig[6000];
    __shared__ float lam[1000];
    __shared__ int   wi[1000];
    __shared__ int   cw[1000];
    __shared__ float redf[4];

    const size_t rowTC = (size_t)b * 6000;
    const size_t rowM  = (size_t)b * 1000;

    // --- sigma + row min
    float lmin = FLT_MAX_C;
    for (int t = tid; t < 6000; t += 256) {
        float v = sB[rowTC + t] + zA[rowM + t / 6];
        sig[t] = v;
        lmin = fminf(lmin, v);
    }
#pragma unroll
    for (int off = 32; off > 0; off >>= 1)
        lmin = fminf(lmin, __shfl_down(lmin, off));
    if (lane == 0) redf[wid] = lmin;
    __syncthreads();
    if (tid == 0)
        redf[0] = fminf(fminf(redf[0], redf[1]), fminf(redf[2], redf[3]));
    __syncthreads();
    const float minv = redf[0];

    // --- per-column lam / winner cell; init cw
    for (int m = tid; m < 1000; m += 256) {
        float best = -FLT_MAX_C;
        int bj = 0;
#pragma unroll
        for (int j = 0; j < 6; ++j) {
            const int t = m * 6 + j;
            const float p = (1.0f - phi[rowTC + t]) * (sig[t] - minv);
            if (p > best) { best = p; bj = j; }
        }
        lam[m] = best;
        wi[m] = bj;
        cw[m] = 0;
    }
    __syncthreads();

    // --- top-50 of lam[1000]: wave 0 only, register-resident (ties -> low idx)
    if (wid == 0) {
        float lv[16];
        int wmask = 0;
#pragma unroll
        for (int j = 0; j < 16; ++j) {
            const int m = lane + (j << 6);
            lv[j] = (m < 1000) ? lam[m] : -FLT_MAX_C;
        }
        for (int it = 0; it < 50; ++it) {
            float bv = -FLT_MAX_C;
            int bi = 0x7fffffff;
#pragma unroll
            for (int j = 0; j < 16; ++j) {
                const int m = lane + (j << 6);
                const float v = lv[j];
                if (v > bv || (v == bv && m < bi)) { bv = v; bi = m; }
            }
#pragma unroll
            for (int off = 32; off > 0; off >>= 1) {
                const float ov = __shfl_xor(bv, off);
                const int oi  = __shfl_xor(bi, off);
                if (ov > bv || (ov == bv && oi < bi)) { bv = ov; bi = oi; }
            }
            if ((bi & 63) == lane) {
                const int jj = bi >> 6;
#pragma unroll
                for (int j = 0; j < 16; ++j)       // static indexing
                    if (j == jj) { lv[j] = -FLT_MAX_C; wmask |= (1 << j); }
            }
        }
#pragma unroll
        for (int j = 0; j < 16; ++j)
            if ((wmask >> j) & 1) cw[lane + (j << 6)] = 1;
    }
    __syncthreads();

    // --- write pass (per column), compute lam2
    for (int m = tid; m < 1000; m += 256) {
        const int won = cw[m];
        const int bj = wi[m];
        float cmax = -FLT_MAX_C;
        const size_t base = rowTC + (size_t)m * 6;
#pragma unroll
        for (int j = 0; j < 6; ++j) {
            const int t = m * 6 + j;
            const float y = (won && j == bj) ? tanhf(sig[t]) : 0.0f;
            const float pv = fmaxf(psi[base + j] * decay[t], y);
            const float fv = fmaxf(phi[base + j] * 0.5f, y);
            psin[base + j] = pv;
            xbn[base + j]  = pv;
            phin[base + j] = fv;
            cmax = fmaxf(cmax, pv);
        }
        lam2[rowM + m] = cmax;
    }
}

// ---------------------------------------------------------------------------
extern "C" void kernel_launch(void* const* d_in, const int* in_sizes, int n_in,
                              void* d_out, int out_size, void* d_ws, size_t ws_size,
                              hipStream_t stream)
{
    const float* x_a   = (const float*)d_in[0];  // [512,2048]
    const float* x_b   = (const float*)d_in[1];  // [512,6000]
    const float* phi   = (const float*)d_in[2];  // [512,6000]
    const float* psi   = (const float*)d_in[3];  // [512,6000]
    const float* W_a   = (const float*)d_in[4];  // [1000,2048]
    const float* W_b   = (const float*)d_in[5];  // [6000,6000]
    const float* W_d   = (const float*)d_in[6];  // [2048,1000]
    const float* b_d   = (const float*)d_in[7];  // [2048]
    const float* decay = (const float*)d_in[8];  // [6000]

    float* out  = (float*)d_out;                       // [512,2048]
    float* xbn  = out + (size_t)512 * 2048;            // [512,6000]
    float* phin = xbn + (size_t)512 * 6000;            // [512,6000]
    float* psin = phin + (size_t)512 * 6000;           // [512,6000]

    float* lam2 = (float*)d_ws;          // [512,1000] (2 MB)

    // Staging (round-4/9 proven): z_a in out region (consumed by rowproc
    // before decode GEMM overwrites out); s_b in xbn region (rowproc stages
    // its row into LDS before overwriting).
    float* z_a = out;
    float* s_b = xbn;

    dim3 blk(256);
    // z_a = x_a @ W_a^T   [512,1000], K=2048; grid = 16 bx * 8 by
    gemm_mfma_split<false><<<dim3(16 * 8), blk, 0, stream>>>(x_a, W_a, nullptr, z_a, 512, 1000, 2048);
    // s_b = x_b @ W_b^T   [512,6000], K=6000; grid = 94 bx * 8 by = 752
    gemm_mfma_split<false><<<dim3(94 * 8), blk, 0, stream>>>(x_b, W_b, nullptr, s_b, 512, 6000, 6000);
    // masking pipeline
    rowproc_kernel<<<512, blk, 0, stream>>>(z_a, s_b, phi, psi, decay, xbn, phin, psin, lam2);
    // out = lam2 @ W_d^T + b_d   [512,2048], K=1000; grid = 32 bx * 8 by
    gemm_mfma_split<true><<<dim3(32 * 8), blk, 0, stream>>>(lam2, W_d, b_d, out, 512, 2048, 1000);
}